// Round 1
// baseline (1343.178 us; speedup 1.0000x reference)
//
#include <hip/hip_runtime.h>

namespace {

constexpr int D  = 64;    // channels per head (ch)
constexpr int T  = 2048;  // sequence length
constexpr int TQ = 64;    // queries per block
constexpr int TS = 64;    // keys per tile
constexpr int NT = T / TS;

// Flash-style attention, fp32 vector ALU baseline.
// Block = 256 threads = 16x16 (tx, ty). One block: 1 head, 64 queries.
// S-phase mapping:  t = ty*4+i (rows, broadcast reads), s = tx*4+j (contig reads)
// PV-phase mapping: t = ty*4+i (same rows -> m/l/alpha stay in registers),
//                   c = tx*4+j (contig reads from transposed V)
__global__ __launch_bounds__(256, 2)
void attn_kernel(const float* __restrict__ qkv, float* __restrict__ out) {
    const int h   = blockIdx.y;           // fused batch*head, 0..63
    const int t0  = blockIdx.x * TQ;      // query tile origin
    const int tid = threadIdx.x;
    const int tx  = tid & 15;
    const int ty  = tid >> 4;

    __shared__ float Qs[D][TQ];     // Qs[c][t]
    __shared__ float Ks[D][TS];     // Ks[c][s]
    __shared__ float Vst[TS][D];    // Vst[s][c]  (transposed during staging)
    __shared__ float Ps[TQ][TS];    // P[t][s]
    // total LDS = 4 * 16 KiB = 64 KiB -> 2 blocks/CU

    const float* qbase = qkv + (size_t)h * (3 * D) * T;
    const float* kbase = qbase + (size_t)D * T;
    const float* vbase = qbase + (size_t)(2 * D) * T;

    // ---- stage Q tile: Qs[c][t] (no transpose; global t-contig -> LDS t-contig)
    {
        const int r  = tid >> 4;     // 0..15
        const int s4 = tid & 15;     // float4 column
        #pragma unroll
        for (int rep = 0; rep < 4; rep++) {
            const int c = rep * 16 + r;
            *(float4*)&Qs[c][s4 * 4] =
                *(const float4*)(qbase + (size_t)c * T + t0 + s4 * 4);
        }
    }

    float m_i[4], l_i[4], acc_o[4][4];
    #pragma unroll
    for (int i = 0; i < 4; i++) {
        m_i[i] = -1e30f;
        l_i[i] = 0.0f;
        #pragma unroll
        for (int j = 0; j < 4; j++) acc_o[i][j] = 0.0f;
    }

    for (int kt = 0; kt < NT; kt++) {
        const int s0 = kt * TS;
        __syncthreads();  // sync A: previous iteration's PV readers done
        // ---- stage K (direct) and V (transposed) ----
        {
            const int r  = tid >> 4;
            const int s4 = tid & 15;
            #pragma unroll
            for (int rep = 0; rep < 4; rep++) {
                const int c = rep * 16 + r;
                *(float4*)&Ks[c][s4 * 4] =
                    *(const float4*)(kbase + (size_t)c * T + s0 + s4 * 4);
                const float4 v = *(const float4*)(vbase + (size_t)c * T + s0 + s4 * 4);
                Vst[s4 * 4 + 0][c] = v.x;   // known ~16-way bank conflict on these
                Vst[s4 * 4 + 1][c] = v.y;   // 16 scalar writes/iter (~6% of iter)
                Vst[s4 * 4 + 2][c] = v.z;
                Vst[s4 * 4 + 3][c] = v.w;
            }
        }
        __syncthreads();  // sync B: tiles staged

        // ---- S[t][s] = sum_c Q[c][t]*K[c][s], then *1/8 ----
        float acc[4][4];
        #pragma unroll
        for (int i = 0; i < 4; i++)
            #pragma unroll
            for (int j = 0; j < 4; j++) acc[i][j] = 0.0f;

        #pragma unroll 16
        for (int c = 0; c < D; c++) {
            const float4 q4 = *(const float4*)&Qs[c][ty * 4];  // 4-addr broadcast
            const float4 k4 = *(const float4*)&Ks[c][tx * 4];  // contig, 2-way free
            const float q[4] = {q4.x, q4.y, q4.z, q4.w};
            const float k[4] = {k4.x, k4.y, k4.z, k4.w};
            #pragma unroll
            for (int i = 0; i < 4; i++)
                #pragma unroll
                for (int j = 0; j < 4; j++)
                    acc[i][j] = fmaf(q[i], k[j], acc[i][j]);
        }

        // ---- online softmax; row t = ty*4+i lives in the 16 tx-lanes ----
        float alpha_r[4];
        #pragma unroll
        for (int i = 0; i < 4; i++) {
            #pragma unroll
            for (int j = 0; j < 4; j++) acc[i][j] *= 0.125f;  // scale^2 = 1/8 exact
            float rm = fmaxf(fmaxf(acc[i][0], acc[i][1]), fmaxf(acc[i][2], acc[i][3]));
            #pragma unroll
            for (int off = 1; off < 16; off <<= 1)
                rm = fmaxf(rm, __shfl_xor(rm, off, 64));
            const float mnew = fmaxf(m_i[i], rm);
            alpha_r[i] = __expf(m_i[i] - mnew);
            m_i[i] = mnew;
            float rs = 0.0f;
            #pragma unroll
            for (int j = 0; j < 4; j++) {
                acc[i][j] = __expf(acc[i][j] - mnew);
                rs += acc[i][j];
            }
            #pragma unroll
            for (int off = 1; off < 16; off <<= 1)
                rs += __shfl_xor(rs, off, 64);
            l_i[i] = l_i[i] * alpha_r[i] + rs;
        }

        // write P tile
        #pragma unroll
        for (int i = 0; i < 4; i++) {
            const float4 pv = make_float4(acc[i][0], acc[i][1], acc[i][2], acc[i][3]);
            *(float4*)&Ps[ty * 4 + i][tx * 4] = pv;
        }
        __syncthreads();  // sync C: P visible

        // ---- O[t][c] = alpha*O + P·V ; t = ty*4+i, c = tx*4+j ----
        #pragma unroll
        for (int i = 0; i < 4; i++)
            #pragma unroll
            for (int j = 0; j < 4; j++) acc_o[i][j] *= alpha_r[i];

        #pragma unroll 4
        for (int s4 = 0; s4 < 16; s4++) {
            float p[4][4], v[4][4];
            #pragma unroll
            for (int i = 0; i < 4; i++) {
                const float4 p4 = *(const float4*)&Ps[ty * 4 + i][s4 * 4];  // broadcast
                p[i][0] = p4.x; p[i][1] = p4.y; p[i][2] = p4.z; p[i][3] = p4.w;
            }
            #pragma unroll
            for (int k = 0; k < 4; k++) {
                const float4 v4 = *(const float4*)&Vst[s4 * 4 + k][tx * 4];  // contig
                v[k][0] = v4.x; v[k][1] = v4.y; v[k][2] = v4.z; v[k][3] = v4.w;
            }
            #pragma unroll
            for (int i = 0; i < 4; i++)
                #pragma unroll
                for (int j = 0; j < 4; j++)
                    #pragma unroll
                    for (int k = 0; k < 4; k++)
                        acc_o[i][j] = fmaf(p[i][k], v[k][j], acc_o[i][j]);
        }
    }

    // ---- finalize (1/l stays in owning lanes) and store out[h][c][t] ----
    #pragma unroll
    for (int i = 0; i < 4; i++) {
        const float linv = 1.0f / l_i[i];
        #pragma unroll
        for (int j = 0; j < 4; j++) acc_o[i][j] *= linv;
    }
    float* obase = out + (size_t)h * D * T + t0;
    #pragma unroll
    for (int j = 0; j < 4; j++) {
        const int c = tx * 4 + j;
        const float4 o4 = make_float4(acc_o[0][j], acc_o[1][j], acc_o[2][j], acc_o[3][j]);
        *(float4*)(obase + (size_t)c * T + ty * 4) = o4;
    }
}

} // namespace

extern "C" void kernel_launch(void* const* d_in, const int* in_sizes, int n_in,
                              void* d_out, int out_size, void* d_ws, size_t ws_size,
                              hipStream_t stream) {
    const float* qkv = (const float*)d_in[0];
    float* out = (float*)d_out;
    dim3 grid(T / TQ, 64);  // 32 query tiles x (bs*N_HEADS)=64
    attn_kernel<<<grid, 256, 0, stream>>>(qkv, out);
}

// Round 2
// 308.207 us; speedup vs baseline: 4.3580x; 4.3580x over previous
//
#include <hip/hip_runtime.h>

namespace {

constexpr int D  = 64;    // channels per head
constexpr int T  = 2048;  // sequence length
constexpr int TQ = 64;    // queries per block
constexpr int TS = 64;    // keys per tile
constexpr int NT = T / TS;
// softmax scale folded with log2(e) so we can use exp2 (native v_exp_f32)
constexpr float SCL = 0.125f * 1.44269504088896340736f;

typedef __bf16 bf16x8 __attribute__((ext_vector_type(8)));
typedef float  f32x4  __attribute__((ext_vector_type(4)));
typedef unsigned short u16x4 __attribute__((ext_vector_type(4)));

// round-to-nearest-even fp32 -> bf16 (raw bits); inputs are finite
__device__ inline unsigned short f2bf(float f) {
    unsigned int u = __builtin_bit_cast(unsigned int, f);
    u += 0x7FFFu + ((u >> 16) & 1u);
    return (unsigned short)(u >> 16);
}

// LDS tiles are row-major 64 wide, with 8-element (16B) granules XOR-swizzled
// by ((row>>1)&7) so that both the staging writes and the MFMA fragment
// ds_read_b128 reads hit the 32-bank floor (see session notes: conflict-free).
__device__ inline bf16x8 frag8(const unsigned short* p, int row, int c0) {
    int g = (c0 >> 3) ^ ((row >> 1) & 7);
    return *(const bf16x8*)(p + row * 64 + g * 8);
}
__device__ inline void st4(unsigned short* p, int row, int c0, u16x4 v) {
    int g = (c0 >> 3) ^ ((row >> 1) & 7);
    *(u16x4*)(p + row * 64 + g * 8 + (c0 & 7)) = v;
}

// Flash attention, bf16 MFMA 16x16x32, no-max online softmax (logits bounded:
// |S| <= ||q||*||k||/8 ~ 8 << 88 needed for exp2 overflow).
// Block = 256 threads = 4 waves. One block: 1 head, 64 queries.
// Wave w owns query strip t = w*16 + (lane&15) for S rows, P rows, and O cols.
__global__ __launch_bounds__(256)
void attn_kernel(const float* __restrict__ qkv, float* __restrict__ out) {
    const int h     = blockIdx.y;        // fused batch*head
    const int t0    = blockIdx.x * TQ;   // query tile origin
    const int tid   = threadIdx.x;
    const int lane  = tid & 63;
    const int strip = tid >> 6;          // wave id 0..3
    const int ln    = lane & 15;
    const int q4    = lane >> 4;         // quad 0..3

    __shared__ unsigned short Qs[TQ * D];  // [t][c] bf16, swizzled
    __shared__ unsigned short Ks[TS * D];  // [s][c]
    __shared__ unsigned short Vs[D * TS];  // [c][s]  (native layout!)
    __shared__ unsigned short Ps[TQ * TS]; // [t][s]
    __shared__ float l_lds[TQ];
    // 32 KiB + 256 B -> 4 blocks/CU by LDS

    const float* qb = qkv + (size_t)h * 3 * D * T;
    const float* kb = qb + (size_t)D * T;
    const float* vb = qb + (size_t)(2 * D) * T;

    // ---- stage Q once: transpose [c][t]-global -> [t][c]-LDS, fp32->bf16 ----
    const int s4 = tid & 15;        // column-quad index (t or s)
    const int c0 = (tid >> 4) * 4;  // 4 channel rows per thread
    {
        float fr[4][4];
        #pragma unroll
        for (int r = 0; r < 4; r++)
            *(f32x4*)fr[r] = *(const f32x4*)(qb + (size_t)(c0 + r) * T + t0 + s4 * 4);
        #pragma unroll
        for (int j = 0; j < 4; j++) {
            int trow = s4 * 4 + j;
            u16x4 w = { f2bf(fr[0][j]), f2bf(fr[1][j]), f2bf(fr[2][j]), f2bf(fr[3][j]) };
            st4(Qs, trow, c0, w);
        }
    }
    __syncthreads();

    // Q A-operand fragments: constant across the whole K loop
    const int arow = strip * 16 + ln;   // this wave's t row
    const int kg   = q4 * 8;            // k-granule offset within 32-wide k-block
    const bf16x8 aq0 = frag8(Qs, arow, kg);
    const bf16x8 aq1 = frag8(Qs, arow, 32 + kg);

    f32x4 acc_o[4];
    #pragma unroll
    for (int m = 0; m < 4; m++) acc_o[m] = (f32x4){0.f, 0.f, 0.f, 0.f};
    float l_acc[4] = {0.f, 0.f, 0.f, 0.f};

    for (int kt = 0; kt < NT; kt++) {
        const int s0 = kt * TS;
        // -- global loads issued before barrier A: overlap prev-iter compute --
        float kr[4][4], vr[4][4];
        #pragma unroll
        for (int r = 0; r < 4; r++)
            *(f32x4*)kr[r] = *(const f32x4*)(kb + (size_t)(c0 + r) * T + s0 + s4 * 4);
        #pragma unroll
        for (int r = 0; r < 4; r++)
            *(f32x4*)vr[r] = *(const f32x4*)(vb + (size_t)(c0 + r) * T + s0 + s4 * 4);

        __syncthreads();  // (A) prev iter done reading Ks/Vs

        // K: transpose to [s][c]; 4x(4 bf16) packed b64 writes, conflict-free
        #pragma unroll
        for (int j = 0; j < 4; j++) {
            int srow = s4 * 4 + j;
            u16x4 wk = { f2bf(kr[0][j]), f2bf(kr[1][j]), f2bf(kr[2][j]), f2bf(kr[3][j]) };
            st4(Ks, srow, c0, wk);
        }
        // V: native [c][s] copy
        #pragma unroll
        for (int r = 0; r < 4; r++) {
            u16x4 wv = { f2bf(vr[r][0]), f2bf(vr[r][1]), f2bf(vr[r][2]), f2bf(vr[r][3]) };
            st4(Vs, c0 + r, s4 * 4, wv);
        }
        __syncthreads();  // (B) tiles staged

        // ---- S[t][s] strip: 16t x 64s, K=64 (2 k-frags) => 8 MFMAs ----
        f32x4 accs[4];
        #pragma unroll
        for (int ns = 0; ns < 4; ns++) {
            bf16x8 b0 = frag8(Ks, ns * 16 + ln, kg);
            bf16x8 b1 = frag8(Ks, ns * 16 + ln, 32 + kg);
            f32x4 z = {0.f, 0.f, 0.f, 0.f};
            z = __builtin_amdgcn_mfma_f32_16x16x32_bf16(aq0, b0, z, 0, 0, 0);
            z = __builtin_amdgcn_mfma_f32_16x16x32_bf16(aq1, b1, z, 0, 0, 0);
            accs[ns] = z;
        }

        // ---- softmax, no max subtraction; defer row-sum to epilogue ----
        // D-frag: col = lane&15 -> s, row = q4*4+reg -> t (verified m89/m91)
        #pragma unroll
        for (int ns = 0; ns < 4; ns++) {
            int scol = ns * 16 + ln;
            #pragma unroll
            for (int r = 0; r < 4; r++) {
                float p = exp2f(accs[ns][r] * SCL);
                l_acc[r] += p;
                int trow = strip * 16 + q4 * 4 + r;
                int g = ((scol >> 3) ^ ((trow >> 1) & 7));
                Ps[trow * 64 + g * 8 + (scol & 7)] = f2bf(p);
            }
        }
        // P rows are wave-private (written and read by this wave only):
        // same-wave LDS RAW needs only lgkmcnt, no barrier.

        // ---- O[c][t-strip] += V * P^T : A=Vs (native), B=Ps rows=t ----
        bf16x8 bp0 = frag8(Ps, arow, kg);
        bf16x8 bp1 = frag8(Ps, arow, 32 + kg);
        #pragma unroll
        for (int ms = 0; ms < 4; ms++) {
            bf16x8 av0 = frag8(Vs, ms * 16 + ln, kg);
            bf16x8 av1 = frag8(Vs, ms * 16 + ln, 32 + kg);
            acc_o[ms] = __builtin_amdgcn_mfma_f32_16x16x32_bf16(av0, bp0, acc_o[ms], 0, 0, 0);
            acc_o[ms] = __builtin_amdgcn_mfma_f32_16x16x32_bf16(av1, bp1, acc_o[ms], 0, 0, 0);
        }
    }

    // ---- epilogue: reduce l across the 16 lanes of each quad-group ----
    #pragma unroll
    for (int r = 0; r < 4; r++) {
        float s = l_acc[r];
        s += __shfl_xor(s, 1, 64);
        s += __shfl_xor(s, 2, 64);
        s += __shfl_xor(s, 4, 64);
        s += __shfl_xor(s, 8, 64);
        if (ln == 0) l_lds[strip * 16 + q4 * 4 + r] = s;
    }
    // written/read by the same wave: no barrier needed
    const float linv = 1.0f / l_lds[strip * 16 + ln];

    // O D-frag: col = lane&15 -> t, row = q4*4+reg -> c. Store out[h][c][t].
    const int tg = t0 + strip * 16 + ln;
    float* ob = out + (size_t)h * D * T;
    #pragma unroll
    for (int ms = 0; ms < 4; ms++)
        #pragma unroll
        for (int r = 0; r < 4; r++) {
            int c = ms * 16 + q4 * 4 + r;
            ob[(size_t)c * T + tg] = acc_o[ms][r] * linv;
        }
}

} // namespace

extern "C" void kernel_launch(void* const* d_in, const int* in_sizes, int n_in,
                              void* d_out, int out_size, void* d_ws, size_t ws_size,
                              hipStream_t stream) {
    const float* qkv = (const float*)d_in[0];
    float* out = (float*)d_out;
    dim3 grid(T / TQ, 64);  // 32 query tiles x (bs*N_HEADS)=64
    attn_kernel<<<grid, 256, 0, stream>>>(qkv, out);
}

// Round 3
// 257.660 us; speedup vs baseline: 5.2130x; 1.1962x over previous
//
#include <hip/hip_runtime.h>

namespace {

constexpr int D  = 64;    // channels per head
constexpr int T  = 2048;  // sequence length
constexpr int TQ = 64;    // queries per block
constexpr int NT = T / 64;
constexpr float SCL = 0.125f * 1.44269504088896340736f;  // scale^2 * log2(e)

// workspace layout (units: unsigned short):
//  [0, 64*32*8192)            KV tiles: (h*32+kt)*8192 ; K swizzled [s][c] first 4096, V [c][s] next 4096
//  [QP_OFF, QP_OFF+64*32*4096) Q tiles: (h*32+qt)*4096 swizzled [t][c]
constexpr size_t QP_OFF  = (size_t)64 * 32 * 8192;
constexpr size_t WS_NEED = ((size_t)64 * 32 * 8192 + (size_t)64 * 32 * 4096) * 2;  // bytes = 50331648

typedef __bf16 bf16x8 __attribute__((ext_vector_type(8)));
typedef float  f32x4  __attribute__((ext_vector_type(4)));
typedef unsigned short u16x4 __attribute__((ext_vector_type(4)));

__device__ inline unsigned short f2bf(float f) {   // RNE fp32->bf16, finite inputs
    unsigned int u = __builtin_bit_cast(unsigned int, f);
    u += 0x7FFFu + ((u >> 16) & 1u);
    return (unsigned short)(u >> 16);
}

// 64-wide rows, 16B granules XOR-swizzled by ((row>>1)&7): staging writes,
// b64 P writes and all b128 fragment reads stay at the 2-way (free) floor.
__device__ inline bf16x8 frag8(const unsigned short* p, int row, int c0) {
    int g = (c0 >> 3) ^ ((row >> 1) & 7);
    return *(const bf16x8*)(p + row * 64 + g * 8);
}

__device__ inline void async_cp16(const void* g, void* l) {
    __builtin_amdgcn_global_load_lds(
        (const __attribute__((address_space(1))) unsigned int*)g,
        (__attribute__((address_space(3))) unsigned int*)l, 16, 0, 0);
}

// ---------------- pre-pass: fp32 -> bf16, swizzled tile layouts ----------------
// grid (32 tiles, 64 heads, 3 mats): z=0 Q (transpose), z=1 K (transpose), z=2 V (copy)
__global__ __launch_bounds__(256)
void prepass(const float* __restrict__ qkv, unsigned short* __restrict__ ws) {
    const int tile = blockIdx.x, h = blockIdx.y, z = blockIdx.z;
    const int tid = threadIdx.x;
    const int c0 = (tid >> 4) * 4;   // 4 channel rows per thread
    const int s4 = tid & 15;         // column quad (t or s)
    const float* src = qkv + (size_t)h * 3 * D * T + (size_t)z * D * T + tile * 64;
    unsigned short* dst = (z == 0)
        ? ws + QP_OFF + (size_t)(h * 32 + tile) * 4096
        : ws + (size_t)(h * 32 + tile) * 8192 + (z == 2 ? 4096 : 0);

    float fr[4][4];
    #pragma unroll
    for (int r = 0; r < 4; r++)
        *(f32x4*)fr[r] = *(const f32x4*)(src + (size_t)(c0 + r) * T + s4 * 4);

    if (z < 2) {  // transpose [c][t] -> [t][c], swizzled
        #pragma unroll
        for (int j = 0; j < 4; j++) {
            int trow = s4 * 4 + j;
            int g = (c0 >> 3) ^ ((trow >> 1) & 7);
            u16x4 w = { f2bf(fr[0][j]), f2bf(fr[1][j]), f2bf(fr[2][j]), f2bf(fr[3][j]) };
            *(u16x4*)(dst + trow * 64 + g * 8 + (c0 & 7)) = w;
        }
    } else {      // V: [c][s] copy, swizzled
        #pragma unroll
        for (int r = 0; r < 4; r++) {
            int row = c0 + r, cc = s4 * 4;
            int g = (cc >> 3) ^ ((row >> 1) & 7);
            u16x4 w = { f2bf(fr[r][0]), f2bf(fr[r][1]), f2bf(fr[r][2]), f2bf(fr[r][3]) };
            *(u16x4*)(dst + row * 64 + g * 8 + (cc & 7)) = w;
        }
    }
}

// ---------------- main: flash attention, 16x16x32 bf16 MFMA ----------------
// Block = 4 waves. Wave w: sh=w&1 (s-half), th=w>>1 (t-half).
// S-phase: S^T[s-half][t-half] (Q frags loop-invariant in regs).
// P round-trip through LDS is wave-local (no barrier). PV: per-s-half O
// partials over all 64 c, merged once in epilogue. 1 barrier/iter.
__global__ __launch_bounds__(256, 4)
void attn_main(const unsigned short* __restrict__ ws, float* __restrict__ out) {
    const int h  = blockIdx.x;      // head on fixed XCD (h%8) for L2 locality
    const int qt = blockIdx.y;
    const int t0 = qt * TQ;
    const int tid  = threadIdx.x;
    const int lane = tid & 63;
    const int w    = tid >> 6;
    const int sh   = w & 1, th = w >> 1;
    const int ln   = lane & 15, q4 = lane >> 4;

    __shared__ unsigned short KV[2][8192];  // [buf][K 4096 | V 4096]
    __shared__ unsigned short Ps[4096];     // P^T staging, wave-disjoint granules
    // 40960 B total -> 4 blocks/CU

    // Q fragments (loop-invariant): B-operand rows t, k-granules over c
    const unsigned short* qtile = ws + QP_OFF + (size_t)(h * 32 + qt) * 4096;
    bf16x8 bQ[2][2];
    #pragma unroll
    for (int ti = 0; ti < 2; ti++)
        #pragma unroll
        for (int kc = 0; kc < 2; kc++) {
            int t = th * 32 + ti * 16 + ln;
            int g = (kc * 4 + q4) ^ ((t >> 1) & 7);
            bQ[ti][kc] = *(const bf16x8*)(qtile + t * 64 + g * 8);
        }

    const char* kvbase = (const char*)ws + (size_t)(h * 32) * 16384
                         + (size_t)w * 4096 + lane * 16;
    {   // stage kt=0 -> buf 0 (each wave: 4 KB = 4 async 16B/lane loads)
        char* l = (char*)&KV[0][0] + w * 4096;
        #pragma unroll
        for (int i = 0; i < 4; i++) async_cp16(kvbase + i * 1024, l + i * 1024);
    }

    f32x4 acc_o[4][2];   // [ci][ti], partial over this wave's s-half
    #pragma unroll
    for (int ci = 0; ci < 4; ci++)
        #pragma unroll
        for (int ti = 0; ti < 2; ti++) acc_o[ci][ti] = (f32x4){0.f, 0.f, 0.f, 0.f};
    float l_acc[2] = {0.f, 0.f};

    for (int kt = 0; kt < NT; kt++) {
        const int buf = kt & 1;
        __syncthreads();  // staged tile ready (vmcnt drained) + prev buf free
        if (kt + 1 < NT) {
            const char* g = kvbase + (size_t)(kt + 1) * 16384;
            char* l = (char*)&KV[buf ^ 1][0] + w * 4096;
            #pragma unroll
            for (int i = 0; i < 4; i++) async_cp16(g + i * 1024, l + i * 1024);
        }
        const unsigned short* Kr = &KV[buf][0];
        const unsigned short* Vr = &KV[buf][4096];

        // ---- S^T[s-half][t-half]: 2x2 tiles x 2 k-chunks = 8 MFMAs ----
        f32x4 acc_s[2][2];
        #pragma unroll
        for (int si = 0; si < 2; si++)
            #pragma unroll
            for (int ti = 0; ti < 2; ti++) acc_s[si][ti] = (f32x4){0.f, 0.f, 0.f, 0.f};
        #pragma unroll
        for (int kc = 0; kc < 2; kc++)
            #pragma unroll
            for (int si = 0; si < 2; si++) {
                bf16x8 aK = frag8(Kr, sh * 32 + si * 16 + ln, kc * 32 + q4 * 8);
                #pragma unroll
                for (int ti = 0; ti < 2; ti++)
                    acc_s[si][ti] = __builtin_amdgcn_mfma_f32_16x16x32_bf16(
                        aK, bQ[ti][kc], acc_s[si][ti], 0, 0, 0);
            }

        // ---- no-max softmax (logits bounded ~|8|): lane-private l, packed P ----
        // D-frag of S^T: col=ln -> t, row=q4*4+r -> s  => 4 consecutive s per reg set
        #pragma unroll
        for (int si = 0; si < 2; si++)
            #pragma unroll
            for (int ti = 0; ti < 2; ti++) {
                float p0 = __builtin_amdgcn_exp2f(acc_s[si][ti][0] * SCL);
                float p1 = __builtin_amdgcn_exp2f(acc_s[si][ti][1] * SCL);
                float p2 = __builtin_amdgcn_exp2f(acc_s[si][ti][2] * SCL);
                float p3 = __builtin_amdgcn_exp2f(acc_s[si][ti][3] * SCL);
                l_acc[ti] += (p0 + p1) + (p2 + p3);
                u16x4 pk = { f2bf(p0), f2bf(p1), f2bf(p2), f2bf(p3) };
                int t  = th * 32 + ti * 16 + ln;
                int c0 = sh * 32 + si * 16 + q4 * 4;
                int g  = (c0 >> 3) ^ ((t >> 1) & 7);
                *(u16x4*)(Ps + t * 64 + g * 8 + (c0 & 7)) = pk;  // b64, 2-way floor
            }

        // ---- PV: O_partial[64c][t-half] over this wave's s-half (k=32) ----
        // P written and read by the SAME wave: lgkmcnt ordering only, no barrier.
        bf16x8 bP[2];
        #pragma unroll
        for (int ti = 0; ti < 2; ti++)
            bP[ti] = frag8(Ps, th * 32 + ti * 16 + ln, sh * 32 + q4 * 8);
        #pragma unroll
        for (int ci = 0; ci < 4; ci++) {
            bf16x8 aV = frag8(Vr, ci * 16 + ln, sh * 32 + q4 * 8);
            #pragma unroll
            for (int ti = 0; ti < 2; ti++)
                acc_o[ci][ti] = __builtin_amdgcn_mfma_f32_16x16x32_bf16(
                    aV, bP[ti], acc_o[ci][ti], 0, 0, 0);
        }
    }

    // ---- epilogue: merge s-half partials (O and l) via dead LDS ----
    __syncthreads();                      // all PV reads of Ps/KV done
    float* mrg = (float*)&KV[0][0];       // 16 KB: th*2048 floats per t-half
    float* lp  = (float*)Ps;
    #pragma unroll
    for (int ti = 0; ti < 2; ti++) {      // reduce l over q4 groups (s coverage)
        float s = l_acc[ti];
        s += __shfl_xor(s, 16, 64);
        s += __shfl_xor(s, 32, 64);
        if (q4 == 0) lp[th * 64 + sh * 32 + ti * 16 + ln] = s;
    }
    if (sh == 0) {
        float* base = mrg + th * 2048;
        #pragma unroll
        for (int ci = 0; ci < 4; ci++)
            #pragma unroll
            for (int ti = 0; ti < 2; ti++)
                *(f32x4*)(base + (ci * 2 + ti) * 256 + lane * 4) = acc_o[ci][ti];
    }
    __syncthreads();
    if (sh == 1) {
        float* base = mrg + th * 2048;
        float linv[2];
        #pragma unroll
        for (int ti = 0; ti < 2; ti++) {
            int tt = ti * 16 + ln;
            linv[ti] = 1.0f / (lp[th * 64 + tt] + lp[th * 64 + 32 + tt]);
        }
        float* ob = out + (size_t)h * D * T + t0 + th * 32;
        #pragma unroll
        for (int ci = 0; ci < 4; ci++)
            #pragma unroll
            for (int ti = 0; ti < 2; ti++) {
                f32x4 part = *(const f32x4*)(base + (ci * 2 + ti) * 256 + lane * 4);
                #pragma unroll
                for (int r = 0; r < 4; r++) {
                    int c = ci * 16 + q4 * 4 + r;
                    ob[(size_t)c * T + ti * 16 + ln] =
                        (acc_o[ci][ti][r] + part[r]) * linv[ti];
                }
            }
    }
}

// ---------------- fallback (R2 kernel, proven): used if ws too small ----------------
__global__ __launch_bounds__(256)
void attn_fallback(const float* __restrict__ qkv, float* __restrict__ out) {
    const int h     = blockIdx.y;
    const int t0    = blockIdx.x * TQ;
    const int tid   = threadIdx.x;
    const int lane  = tid & 63;
    const int strip = tid >> 6;
    const int ln    = lane & 15;
    const int q4    = lane >> 4;

    __shared__ unsigned short Qs[TQ * D];
    __shared__ unsigned short Ks[64 * D];
    __shared__ unsigned short Vs[D * 64];
    __shared__ unsigned short Pss[TQ * 64];
    __shared__ float l_lds[TQ];

    const float* qb = qkv + (size_t)h * 3 * D * T;
    const float* kb = qb + (size_t)D * T;
    const float* vb = qb + (size_t)(2 * D) * T;
    const int s4 = tid & 15;
    const int c0 = (tid >> 4) * 4;
    {
        float fr[4][4];
        #pragma unroll
        for (int r = 0; r < 4; r++)
            *(f32x4*)fr[r] = *(const f32x4*)(qb + (size_t)(c0 + r) * T + t0 + s4 * 4);
        #pragma unroll
        for (int j = 0; j < 4; j++) {
            int trow = s4 * 4 + j;
            int g = (c0 >> 3) ^ ((trow >> 1) & 7);
            u16x4 wv = { f2bf(fr[0][j]), f2bf(fr[1][j]), f2bf(fr[2][j]), f2bf(fr[3][j]) };
            *(u16x4*)(Qs + trow * 64 + g * 8 + (c0 & 7)) = wv;
        }
    }
    __syncthreads();
    const int arow = strip * 16 + ln;
    const int kg   = q4 * 8;
    const bf16x8 aq0 = frag8(Qs, arow, kg);
    const bf16x8 aq1 = frag8(Qs, arow, 32 + kg);
    f32x4 acc_o[4];
    #pragma unroll
    for (int m = 0; m < 4; m++) acc_o[m] = (f32x4){0.f, 0.f, 0.f, 0.f};
    float l_acc[4] = {0.f, 0.f, 0.f, 0.f};
    for (int kt = 0; kt < NT; kt++) {
        const int s0 = kt * 64;
        float kr[4][4], vr[4][4];
        #pragma unroll
        for (int r = 0; r < 4; r++)
            *(f32x4*)kr[r] = *(const f32x4*)(kb + (size_t)(c0 + r) * T + s0 + s4 * 4);
        #pragma unroll
        for (int r = 0; r < 4; r++)
            *(f32x4*)vr[r] = *(const f32x4*)(vb + (size_t)(c0 + r) * T + s0 + s4 * 4);
        __syncthreads();
        #pragma unroll
        for (int j = 0; j < 4; j++) {
            int srow = s4 * 4 + j;
            int g = (c0 >> 3) ^ ((srow >> 1) & 7);
            u16x4 wk = { f2bf(kr[0][j]), f2bf(kr[1][j]), f2bf(kr[2][j]), f2bf(kr[3][j]) };
            *(u16x4*)(Ks + srow * 64 + g * 8 + (c0 & 7)) = wk;
        }
        #pragma unroll
        for (int r = 0; r < 4; r++) {
            int row = c0 + r, cc = s4 * 4;
            int g = (cc >> 3) ^ ((row >> 1) & 7);
            u16x4 wv = { f2bf(vr[r][0]), f2bf(vr[r][1]), f2bf(vr[r][2]), f2bf(vr[r][3]) };
            *(u16x4*)(Vs + row * 64 + g * 8 + (cc & 7)) = wv;
        }
        __syncthreads();
        f32x4 accs[4];
        #pragma unroll
        for (int ns = 0; ns < 4; ns++) {
            bf16x8 b0 = frag8(Ks, ns * 16 + ln, kg);
            bf16x8 b1 = frag8(Ks, ns * 16 + ln, 32 + kg);
            f32x4 z = {0.f, 0.f, 0.f, 0.f};
            z = __builtin_amdgcn_mfma_f32_16x16x32_bf16(aq0, b0, z, 0, 0, 0);
            z = __builtin_amdgcn_mfma_f32_16x16x32_bf16(aq1, b1, z, 0, 0, 0);
            accs[ns] = z;
        }
        #pragma unroll
        for (int ns = 0; ns < 4; ns++) {
            int scol = ns * 16 + ln;
            #pragma unroll
            for (int r = 0; r < 4; r++) {
                float p = __builtin_amdgcn_exp2f(accs[ns][r] * SCL);
                l_acc[r] += p;
                int trow = strip * 16 + q4 * 4 + r;
                int g = ((scol >> 3) ^ ((trow >> 1) & 7));
                Pss[trow * 64 + g * 8 + (scol & 7)] = f2bf(p);
            }
        }
        bf16x8 bp0 = frag8(Pss, arow, kg);
        bf16x8 bp1 = frag8(Pss, arow, 32 + kg);
        #pragma unroll
        for (int ms = 0; ms < 4; ms++) {
            bf16x8 av0 = frag8(Vs, ms * 16 + ln, kg);
            bf16x8 av1 = frag8(Vs, ms * 16 + ln, 32 + kg);
            acc_o[ms] = __builtin_amdgcn_mfma_f32_16x16x32_bf16(av0, bp0, acc_o[ms], 0, 0, 0);
            acc_o[ms] = __builtin_amdgcn_mfma_f32_16x16x32_bf16(av1, bp1, acc_o[ms], 0, 0, 0);
        }
    }
    #pragma unroll
    for (int r = 0; r < 4; r++) {
        float s = l_acc[r];
        s += __shfl_xor(s, 1, 64);
        s += __shfl_xor(s, 2, 64);
        s += __shfl_xor(s, 4, 64);
        s += __shfl_xor(s, 8, 64);
        if (ln == 0) l_lds[strip * 16 + q4 * 4 + r] = s;
    }
    const float linv = 1.0f / l_lds[strip * 16 + ln];
    const int tg = t0 + strip * 16 + ln;
    float* ob = out + (size_t)h * D * T;
    #pragma unroll
    for (int ms = 0; ms < 4; ms++)
        #pragma unroll
        for (int r = 0; r < 4; r++) {
            int c = ms * 16 + q4 * 4 + r;
            ob[(size_t)c * T + tg] = acc_o[ms][r] * linv;
        }
}

} // namespace

extern "C" void kernel_launch(void* const* d_in, const int* in_sizes, int n_in,
                              void* d_out, int out_size, void* d_ws, size_t ws_size,
                              hipStream_t stream) {
    const float* qkv = (const float*)d_in[0];
    float* out = (float*)d_out;
    if (ws_size >= WS_NEED) {
        prepass<<<dim3(32, 64, 3), 256, 0, stream>>>(qkv, (unsigned short*)d_ws);
        // grid (h, qt): consecutive blocks differ in h -> head h pinned to XCD h%8,
        // per-head 512 KB K/V tile stream stays L2-resident.
        attn_main<<<dim3(64, 32), 256, 0, stream>>>((const unsigned short*)d_ws, out);
    } else {
        attn_fallback<<<dim3(32, 64), 256, 0, stream>>>(qkv, out);
    }
}

// Round 4
// 255.668 us; speedup vs baseline: 5.2536x; 1.0078x over previous
//
#include <hip/hip_runtime.h>

namespace {

constexpr int D  = 64;    // channels per head
constexpr int T  = 2048;  // sequence length
constexpr int TQ = 64;    // queries per block
constexpr int NT = T / 64;
constexpr float SCL = 0.125f * 1.44269504088896340736f;  // scale^2 * log2(e)

// workspace layout (units: unsigned short):
//  [0, 64*32*8192)             KV tiles: (h*32+kt)*8192 ; K swizzled [s][c] first 4096, V [c][s] next 4096
//  [QP_OFF, QP_OFF+64*32*4096) Q tiles: (h*32+qt)*4096 swizzled [t][c], PRE-SCALED by SCL
constexpr size_t QP_OFF  = (size_t)64 * 32 * 8192;
constexpr size_t WS_NEED = ((size_t)64 * 32 * 8192 + (size_t)64 * 32 * 4096) * 2;  // 50331648 B

typedef __bf16 bf16x8 __attribute__((ext_vector_type(8)));
typedef float  f32x4  __attribute__((ext_vector_type(4)));
typedef unsigned short u16x4 __attribute__((ext_vector_type(4)));
typedef unsigned short u16x8 __attribute__((ext_vector_type(8)));

__device__ inline unsigned short f2bf(float f) {   // RNE fp32->bf16, finite inputs
    unsigned int u = __builtin_bit_cast(unsigned int, f);
    u += 0x7FFFu + ((u >> 16) & 1u);
    return (unsigned short)(u >> 16);
}

// 64-wide rows, 16B granules XOR-swizzled by ((row>>1)&7): staging writes,
// b64 P writes and all b128 fragment reads stay at the 2-way (free) floor.
__device__ inline int frag_off(int row, int c0) {
    int g = (c0 >> 3) ^ ((row >> 1) & 7);
    return row * 64 + g * 8;
}

__device__ inline void async_cp16(const void* g, void* l) {
    __builtin_amdgcn_global_load_lds(
        (const __attribute__((address_space(1))) unsigned int*)g,
        (__attribute__((address_space(3))) unsigned int*)l, 16, 0, 0);
}

// ---------------- pre-pass v2: fp32 -> bf16, swizzled tiles, COALESCED writes --
// grid (32 tiles, 64 heads, 3): z=0 Q (transpose, pre-scaled), z=1 K (transpose),
// z=2 V (row copy). Q/K build the swizzled [t][c] image in LDS (proven staging
// pattern), then copy LDS->global linearly as 16B stores.
__global__ __launch_bounds__(256)
void prepass(const float* __restrict__ qkv, unsigned short* __restrict__ ws) {
    const int tile = blockIdx.x, h = blockIdx.y, z = blockIdx.z;
    const int tid = threadIdx.x;
    const float* src = qkv + (size_t)h * 3 * D * T + (size_t)z * D * T + tile * 64;
    __shared__ unsigned short L[4096];

    if (z == 2) {  // V: [c][s] granule-swizzled rows; 16B coalesced stores
        unsigned short* dst = ws + (size_t)(h * 32 + tile) * 8192 + 4096;
        #pragma unroll
        for (int half = 0; half < 2; half++) {
            int idx = half * 256 + tid;        // output granule 0..511
            int row = idx >> 3, g = idx & 7;
            int gg  = g ^ ((row >> 1) & 7);    // source granule
            f32x4 a = *(const f32x4*)(src + (size_t)row * T + gg * 8);
            f32x4 b = *(const f32x4*)(src + (size_t)row * T + gg * 8 + 4);
            u16x8 wv = { f2bf(a[0]), f2bf(a[1]), f2bf(a[2]), f2bf(a[3]),
                         f2bf(b[0]), f2bf(b[1]), f2bf(b[2]), f2bf(b[3]) };
            *(u16x8*)(dst + idx * 8) = wv;     // = dst + row*64 + g*8
        }
    } else {       // Q/K: transpose [c][t] -> swizzled [t][c] via LDS
        const float m = (z == 0) ? SCL : 1.0f;   // fold softmax scale into Q
        const int c0 = (tid >> 4) * 4, s4 = tid & 15;
        float fr[4][4];
        #pragma unroll
        for (int r = 0; r < 4; r++)
            *(f32x4*)fr[r] = *(const f32x4*)(src + (size_t)(c0 + r) * T + s4 * 4);
        #pragma unroll
        for (int j = 0; j < 4; j++) {
            int trow = s4 * 4 + j;
            u16x4 wv = { f2bf(fr[0][j] * m), f2bf(fr[1][j] * m),
                         f2bf(fr[2][j] * m), f2bf(fr[3][j] * m) };
            *(u16x4*)(L + frag_off(trow, c0) + (c0 & 7)) = wv;  // 2-way floor
        }
        __syncthreads();
        unsigned short* dst = (z == 0)
            ? ws + QP_OFF + (size_t)(h * 32 + tile) * 4096
            : ws + (size_t)(h * 32 + tile) * 8192;
        #pragma unroll
        for (int i = 0; i < 2; i++)   // linear image copy: conflict-free reads,
            *(u16x8*)(dst + tid * 16 + i * 8) =          // coalesced 16B stores
                *(const u16x8*)(L + tid * 16 + i * 8);
    }
}

// ---------------- main: flash attention, 16x16x32 bf16 MFMA ----------------
// Block = 4 waves. Wave w: sh=w&1 (s-half), th=w>>1 (t-half).
// All LDS fragment addresses precomputed; K-loop hand-unrolled x2 so the
// double-buffer index is a literal -> zero per-iter address VALU.
// P round-trip through LDS is wave-local (no barrier). 1 barrier/iter.

#define ATTN_BODY(KT, B)                                                      \
  {                                                                           \
    const int kt_ = (KT);                                                     \
    __syncthreads(); /* staged tile ready (vmcnt drained) + prev buf free */  \
    if (kt_ < NT - 1) {                                                       \
      const char* gsrc = kvbase + (size_t)(kt_ + 1) * 16384;                  \
      _Pragma("unroll")                                                       \
      for (int i = 0; i < 4; i++)                                             \
        async_cp16(gsrc + i * 1024, stage[(B) ^ 1] + i * 1024);               \
    }                                                                         \
    f32x4 acc_s[2][2];                                                        \
    _Pragma("unroll")                                                         \
    for (int si = 0; si < 2; si++)                                            \
      _Pragma("unroll")                                                       \
      for (int ti = 0; ti < 2; ti++)                                          \
        acc_s[si][ti] = (f32x4){0.f, 0.f, 0.f, 0.f};                          \
    _Pragma("unroll")                                                         \
    for (int kc = 0; kc < 2; kc++)                                            \
      _Pragma("unroll")                                                       \
      for (int si = 0; si < 2; si++) {                                        \
        bf16x8 aK = *(const bf16x8*)aKp[B][kc][si];                           \
        _Pragma("unroll")                                                     \
        for (int ti = 0; ti < 2; ti++)                                        \
          acc_s[si][ti] = __builtin_amdgcn_mfma_f32_16x16x32_bf16(            \
              aK, bQ[ti][kc], acc_s[si][ti], 0, 0, 0);                        \
      }                                                                       \
    /* no-max softmax: Q pre-scaled, so P = exp2(acc) directly */             \
    _Pragma("unroll")                                                         \
    for (int si = 0; si < 2; si++)                                            \
      _Pragma("unroll")                                                       \
      for (int ti = 0; ti < 2; ti++) {                                        \
        float p0 = __builtin_amdgcn_exp2f(acc_s[si][ti][0]);                  \
        float p1 = __builtin_amdgcn_exp2f(acc_s[si][ti][1]);                  \
        float p2 = __builtin_amdgcn_exp2f(acc_s[si][ti][2]);                  \
        float p3 = __builtin_amdgcn_exp2f(acc_s[si][ti][3]);                  \
        l_acc[ti] += (p0 + p1) + (p2 + p3);                                   \
        u16x4 pk = { f2bf(p0), f2bf(p1), f2bf(p2), f2bf(p3) };                \
        *(u16x4*)pwp[si][ti] = pk;                                            \
      }                                                                       \
    /* P written+read by SAME wave: lgkmcnt ordering only, no barrier */      \
    bf16x8 bP0 = *(const bf16x8*)bPp[0];                                      \
    bf16x8 bP1 = *(const bf16x8*)bPp[1];                                      \
    _Pragma("unroll")                                                         \
    for (int ci = 0; ci < 4; ci++) {                                          \
      bf16x8 aV = *(const bf16x8*)aVp[B][ci];                                 \
      acc_o[ci][0] = __builtin_amdgcn_mfma_f32_16x16x32_bf16(                 \
          aV, bP0, acc_o[ci][0], 0, 0, 0);                                    \
      acc_o[ci][1] = __builtin_amdgcn_mfma_f32_16x16x32_bf16(                 \
          aV, bP1, acc_o[ci][1], 0, 0, 0);                                    \
    }                                                                         \
  }

__global__ __launch_bounds__(256, 4)
void attn_main(const unsigned short* __restrict__ ws, float* __restrict__ out) {
    const int h  = blockIdx.x;      // head pinned to XCD h%8 for L2 locality
    const int qt = blockIdx.y;
    const int t0 = qt * TQ;
    const int tid  = threadIdx.x;
    const int lane = tid & 63;
    const int w    = tid >> 6;
    const int sh   = w & 1, th = w >> 1;
    const int ln   = lane & 15, q4 = lane >> 4;

    __shared__ unsigned short KV[2][8192];  // [buf][K 4096 | V 4096]
    __shared__ unsigned short Ps[4096];     // P^T staging, wave-disjoint granules
    // 40960 B -> 4 blocks/CU

    // Q fragments (loop-invariant, PRE-SCALED in prepass)
    const unsigned short* qtile = ws + QP_OFF + (size_t)(h * 32 + qt) * 4096;
    bf16x8 bQ[2][2];
    #pragma unroll
    for (int ti = 0; ti < 2; ti++)
        #pragma unroll
        for (int kc = 0; kc < 2; kc++) {
            int t = th * 32 + ti * 16 + ln;
            bQ[ti][kc] = *(const bf16x8*)(qtile + frag_off(t, kc * 32 + q4 * 8));
        }

    // ---- precompute every LDS address once ----
    const unsigned short* aKp[2][2][2];   // [buf][kc][si]
    const unsigned short* aVp[2][4];      // [buf][ci]
    const unsigned short* bPp[2];         // [ti]
    unsigned short*       pwp[2][2];      // [si][ti]
    char*                 stage[2];
    #pragma unroll
    for (int b = 0; b < 2; b++) {
        const unsigned short* Kr = &KV[b][0];
        const unsigned short* Vr = &KV[b][4096];
        #pragma unroll
        for (int kc = 0; kc < 2; kc++)
            #pragma unroll
            for (int si = 0; si < 2; si++)
                aKp[b][kc][si] = Kr + frag_off(sh * 32 + si * 16 + ln, kc * 32 + q4 * 8);
        #pragma unroll
        for (int ci = 0; ci < 4; ci++)
            aVp[b][ci] = Vr + frag_off(ci * 16 + ln, sh * 32 + q4 * 8);
        stage[b] = (char*)&KV[b][0] + w * 4096;
    }
    #pragma unroll
    for (int ti = 0; ti < 2; ti++) {
        bPp[ti] = Ps + frag_off(th * 32 + ti * 16 + ln, sh * 32 + q4 * 8);
        #pragma unroll
        for (int si = 0; si < 2; si++) {
            int t = th * 32 + ti * 16 + ln, c0p = sh * 32 + si * 16 + q4 * 4;
            pwp[si][ti] = Ps + frag_off(t, c0p) + (c0p & 7);
        }
    }

    const char* kvbase = (const char*)ws + (size_t)(h * 32) * 16384
                         + (size_t)w * 4096 + lane * 16;
    #pragma unroll
    for (int i = 0; i < 4; i++) async_cp16(kvbase + i * 1024, stage[0] + i * 1024);

    f32x4 acc_o[4][2];   // [ci][ti], partial over this wave's s-half
    #pragma unroll
    for (int ci = 0; ci < 4; ci++)
        #pragma unroll
        for (int ti = 0; ti < 2; ti++) acc_o[ci][ti] = (f32x4){0.f, 0.f, 0.f, 0.f};
    float l_acc[2] = {0.f, 0.f};

    #pragma unroll 1
    for (int m = 0; m < NT / 2; m++) {
        ATTN_BODY(2 * m,     0)
        ATTN_BODY(2 * m + 1, 1)
    }

    // ---- epilogue: merge s-half partials (O and l) via dead LDS ----
    __syncthreads();
    float* mrg = (float*)&KV[0][0];
    float* lp  = (float*)Ps;
    #pragma unroll
    for (int ti = 0; ti < 2; ti++) {
        float s = l_acc[ti];
        s += __shfl_xor(s, 16, 64);
        s += __shfl_xor(s, 32, 64);
        if (q4 == 0) lp[th * 64 + sh * 32 + ti * 16 + ln] = s;
    }
    if (sh == 0) {
        float* base = mrg + th * 2048;
        #pragma unroll
        for (int ci = 0; ci < 4; ci++)
            #pragma unroll
            for (int ti = 0; ti < 2; ti++)
                *(f32x4*)(base + (ci * 2 + ti) * 256 + lane * 4) = acc_o[ci][ti];
    }
    __syncthreads();
    if (sh == 1) {
        float* base = mrg + th * 2048;
        float linv[2];
        #pragma unroll
        for (int ti = 0; ti < 2; ti++) {
            int tt = ti * 16 + ln;
            linv[ti] = 1.0f / (lp[th * 64 + tt] + lp[th * 64 + 32 + tt]);
        }
        float* ob = out + (size_t)h * D * T + t0 + th * 32;
        #pragma unroll
        for (int ci = 0; ci < 4; ci++)
            #pragma unroll
            for (int ti = 0; ti < 2; ti++) {
                f32x4 part = *(const f32x4*)(base + (ci * 2 + ti) * 256 + lane * 4);
                #pragma unroll
                for (int r = 0; r < 4; r++) {
                    int c = ci * 16 + q4 * 4 + r;
                    ob[(size_t)c * T + ti * 16 + ln] =
                        (acc_o[ci][ti][r] + part[r]) * linv[ti];
                }
            }
    }
}

// ---------------- fallback (R2 kernel, proven): used if ws too small ----------
__device__ inline bf16x8 frag8(const unsigned short* p, int row, int c0) {
    return *(const bf16x8*)(p + frag_off(row, c0));
}

__global__ __launch_bounds__(256)
void attn_fallback(const float* __restrict__ qkv, float* __restrict__ out) {
    const int h     = blockIdx.y;
    const int t0    = blockIdx.x * TQ;
    const int tid   = threadIdx.x;
    const int lane  = tid & 63;
    const int strip = tid >> 6;
    const int ln    = lane & 15;
    const int q4    = lane >> 4;

    __shared__ unsigned short Qs[TQ * D];
    __shared__ unsigned short Ks[64 * D];
    __shared__ unsigned short Vs[D * 64];
    __shared__ unsigned short Pss[TQ * 64];
    __shared__ float l_lds[TQ];

    const float* qb = qkv + (size_t)h * 3 * D * T;
    const float* kb = qb + (size_t)D * T;
    const float* vb = qb + (size_t)(2 * D) * T;
    const int s4 = tid & 15;
    const int c0 = (tid >> 4) * 4;
    {
        float fr[4][4];
        #pragma unroll
        for (int r = 0; r < 4; r++)
            *(f32x4*)fr[r] = *(const f32x4*)(qb + (size_t)(c0 + r) * T + t0 + s4 * 4);
        #pragma unroll
        for (int j = 0; j < 4; j++) {
            int trow = s4 * 4 + j;
            u16x4 wv = { f2bf(fr[0][j]), f2bf(fr[1][j]), f2bf(fr[2][j]), f2bf(fr[3][j]) };
            *(u16x4*)(Qs + frag_off(trow, c0) + (c0 & 7)) = wv;
        }
    }
    __syncthreads();
    const int arow = strip * 16 + ln;
    const int kg   = q4 * 8;
    const bf16x8 aq0 = frag8(Qs, arow, kg);
    const bf16x8 aq1 = frag8(Qs, arow, 32 + kg);
    f32x4 acc_o[4];
    #pragma unroll
    for (int m = 0; m < 4; m++) acc_o[m] = (f32x4){0.f, 0.f, 0.f, 0.f};
    float l_acc[4] = {0.f, 0.f, 0.f, 0.f};
    constexpr float S2 = 0.125f * 1.44269504088896340736f;
    for (int kt = 0; kt < NT; kt++) {
        const int s0 = kt * 64;
        float kr[4][4], vr[4][4];
        #pragma unroll
        for (int r = 0; r < 4; r++)
            *(f32x4*)kr[r] = *(const f32x4*)(kb + (size_t)(c0 + r) * T + s0 + s4 * 4);
        #pragma unroll
        for (int r = 0; r < 4; r++)
            *(f32x4*)vr[r] = *(const f32x4*)(vb + (size_t)(c0 + r) * T + s0 + s4 * 4);
        __syncthreads();
        #pragma unroll
        for (int j = 0; j < 4; j++) {
            int srow = s4 * 4 + j;
            u16x4 wk = { f2bf(kr[0][j]), f2bf(kr[1][j]), f2bf(kr[2][j]), f2bf(kr[3][j]) };
            *(u16x4*)(Ks + frag_off(srow, c0) + (c0 & 7)) = wk;
        }
        #pragma unroll
        for (int r = 0; r < 4; r++) {
            int row = c0 + r, cc = s4 * 4;
            u16x4 wv = { f2bf(vr[r][0]), f2bf(vr[r][1]), f2bf(vr[r][2]), f2bf(vr[r][3]) };
            *(u16x4*)(Vs + frag_off(row, cc) + (cc & 7)) = wv;
        }
        __syncthreads();
        f32x4 accs[4];
        #pragma unroll
        for (int ns = 0; ns < 4; ns++) {
            bf16x8 b0 = frag8(Ks, ns * 16 + ln, kg);
            bf16x8 b1 = frag8(Ks, ns * 16 + ln, 32 + kg);
            f32x4 z = {0.f, 0.f, 0.f, 0.f};
            z = __builtin_amdgcn_mfma_f32_16x16x32_bf16(aq0, b0, z, 0, 0, 0);
            z = __builtin_amdgcn_mfma_f32_16x16x32_bf16(aq1, b1, z, 0, 0, 0);
            accs[ns] = z;
        }
        #pragma unroll
        for (int ns = 0; ns < 4; ns++) {
            int scol = ns * 16 + ln;
            #pragma unroll
            for (int r = 0; r < 4; r++) {
                float p = __builtin_amdgcn_exp2f(accs[ns][r] * S2);
                l_acc[r] += p;
                int trow = strip * 16 + q4 * 4 + r;
                int g = ((scol >> 3) ^ ((trow >> 1) & 7));
                Pss[trow * 64 + g * 8 + (scol & 7)] = f2bf(p);
            }
        }
        bf16x8 bp0 = frag8(Pss, arow, kg);
        bf16x8 bp1 = frag8(Pss, arow, 32 + kg);
        #pragma unroll
        for (int ms = 0; ms < 4; ms++) {
            bf16x8 av0 = frag8(Vs, ms * 16 + ln, kg);
            bf16x8 av1 = frag8(Vs, ms * 16 + ln, 32 + kg);
            acc_o[ms] = __builtin_amdgcn_mfma_f32_16x16x32_bf16(av0, bp0, acc_o[ms], 0, 0, 0);
            acc_o[ms] = __builtin_amdgcn_mfma_f32_16x16x32_bf16(av1, bp1, acc_o[ms], 0, 0, 0);
        }
    }
    #pragma unroll
    for (int r = 0; r < 4; r++) {
        float s = l_acc[r];
        s += __shfl_xor(s, 1, 64);
        s += __shfl_xor(s, 2, 64);
        s += __shfl_xor(s, 4, 64);
        s += __shfl_xor(s, 8, 64);
        if (ln == 0) l_lds[strip * 16 + q4 * 4 + r] = s;
    }
    const float linv = 1.0f / l_lds[strip * 16 + ln];
    const int tg = t0 + strip * 16 + ln;
    float* ob = out + (size_t)h * D * T;
    #pragma unroll
    for (int ms = 0; ms < 4; ms++)
        #pragma unroll
        for (int r = 0; r < 4; r++) {
            int c = ms * 16 + q4 * 4 + r;
            ob[(size_t)c * T + tg] = acc_o[ms][r] * linv;
        }
}

} // namespace

extern "C" void kernel_launch(void* const* d_in, const int* in_sizes, int n_in,
                              void* d_out, int out_size, void* d_ws, size_t ws_size,
                              hipStream_t stream) {
    const float* qkv = (const float*)d_in[0];
    float* out = (float*)d_out;
    if (ws_size >= WS_NEED) {
        prepass<<<dim3(32, 64, 3), 256, 0, stream>>>(qkv, (unsigned short*)d_ws);
        attn_main<<<dim3(64, 32), 256, 0, stream>>>((const unsigned short*)d_ws, out);
    } else {
        attn_fallback<<<dim3(32, 64), 256, 0, stream>>>(qkv, out);
    }
}